// Round 9
// baseline (1804.209 us; speedup 1.0000x reference)
//
#include <hip/hip_runtime.h>
#include <hip/hip_bf16.h>
#include <math.h>

// Problem constants
#define N_TRAIN 4096
#define N_FEAT  64
#define NHID    256
#define ENC     256
#define GH      256
#define AH      64
#define NANTES  32768
#define TSTEPS  32

#define SSTR 528   // lstm setup LDS row stride (f32)

typedef __attribute__((ext_vector_type(8))) short bf16x8;
typedef __attribute__((ext_vector_type(4))) float f32x4;

__device__ __forceinline__ float sigmoidf_(float x) {
    return 1.0f / (1.0f + __expf(-x));
}
__device__ __forceinline__ float tanhf_(float x) {
    return 1.0f - 2.0f / (__expf(2.0f * x) + 1.0f);
}
__device__ __forceinline__ unsigned short f2bf_rne(float x) {
    unsigned int u = __float_as_uint(x);
    unsigned int r = u + 0x7FFFu + ((u >> 16) & 1u);
    return (unsigned short)(r >> 16);
}
__device__ __forceinline__ float bf2f(unsigned short b) {
    return __uint_as_float(((unsigned int)b) << 16);
}

// ---------------------------------------------------------------------------
// Kernel 0: zero the e-sum accumulator
// ---------------------------------------------------------------------------
__global__ void zero_kernel(float* __restrict__ esum) {
    int tid = blockIdx.x * blockDim.x + threadIdx.x;
    for (int i = tid; i < TSTEPS * GH; i += gridDim.x * blockDim.x)
        esum[i] = 0.0f;
}

// ---------------------------------------------------------------------------
// Kernel P: pack Whh (1024x256 f32) into MFMA-fragment-ordered bf16 (hi only).
// ---------------------------------------------------------------------------
__global__ void pack_whh(const float* __restrict__ Whh,
                         unsigned short* __restrict__ hi)
{
    int g = blockIdx.x * 256 + threadIdx.x;      // 0 .. 32767
    if (g >= 64 * 8 * 64) return;
    int lane  = g & 63;
    int ks    = (g >> 6) & 7;
    int ntile = g >> 9;
    int n  = ntile * 16 + (lane & 15);
    int k0 = ks * 32 + (lane >> 4) * 8;
    const float* src = Whh + n * 256 + k0;
    #pragma unroll
    for (int j = 0; j < 8; ++j)
        hi[g * 8 + j] = f2bf_rne(src[j]);
}

// ---------------------------------------------------------------------------
// Kernel A: fused encoder -> x_proj -> 32-step MFMA LSTM -> per-step h sums
// (unchanged from round 6 — benched without scratch traffic)
// ---------------------------------------------------------------------------
__global__ __launch_bounds__(512, 4) void lstm_kernel(
    const float* __restrict__ ctx,
    const float* __restrict__ encW1, const float* __restrict__ encb1,
    const float* __restrict__ encW2, const float* __restrict__ encb2,
    const float* __restrict__ Wih,
    const float* __restrict__ bih,  const float* __restrict__ bhh,
    const unsigned short* __restrict__ Wph,
    float* __restrict__ esum)
{
    __shared__ float sbuf[16 * SSTR];      // 33792 B setup scratch
    __shared__ short hhi[2][16 * 256];     // 16 KB, XOR-swizzled cols
    __shared__ short hlo[2][16 * 256];     // 16 KB

    const int tid   = threadIdx.x;
    const int j     = tid & 255;
    const int rh    = tid >> 8;
    const int rbase = rh * 8;
    const int r0    = blockIdx.x * 16;

    // hid = relu(ctx @ encW1 + b1) -> sbuf cols [0,256)
    {
        float acc[8];
        float b = encb1[j];
        #pragma unroll
        for (int r = 0; r < 8; ++r) acc[r] = b;
        for (int k = 0; k < N_FEAT; ++k) {
            float w = encW1[k * NHID + j];
            #pragma unroll
            for (int r = 0; r < 8; ++r)
                acc[r] = fmaf(ctx[(r0 + rbase + r) * N_FEAT + k], w, acc[r]);
        }
        #pragma unroll
        for (int r = 0; r < 8; ++r)
            sbuf[(rbase + r) * SSTR + j] = fmaxf(acc[r], 0.0f);
    }
    __syncthreads();

    // phi = hid @ encW2 + b2 -> sbuf cols [264,520)
    {
        float p[8];
        float b = encb2[j];
        #pragma unroll
        for (int r = 0; r < 8; ++r) p[r] = b;
        for (int k = 0; k < NHID; ++k) {
            float w = encW2[k * ENC + j];
            #pragma unroll
            for (int r = 0; r < 8; ++r)
                p[r] = fmaf(sbuf[(rbase + r) * SSTR + k], w, p[r]);
        }
        __syncthreads();
        #pragma unroll
        for (int r = 0; r < 8; ++r)
            sbuf[(rbase + r) * SSTR + 264 + j] = p[r];
    }
    __syncthreads();

    // xp[g][r] in registers (reads phi)
    float xp[4][8];
    #pragma unroll
    for (int g = 0; g < 4; ++g) {
        int m = g * 256 + j;
        float b = bih[m] + bhh[m];
        #pragma unroll
        for (int r = 0; r < 8; ++r) xp[g][r] = b;
        const float4* wrow = (const float4*)(Wih + m * ENC);
        for (int k4 = 0; k4 < ENC / 4; ++k4) {
            float4 wv = wrow[k4];
            #pragma unroll
            for (int r = 0; r < 8; ++r) {
                const float* ph = &sbuf[(rbase + r) * SSTR + 264 + k4 * 4];
                float v = xp[g][r];
                v = fmaf(ph[0], wv.x, v);
                v = fmaf(ph[1], wv.y, v);
                v = fmaf(ph[2], wv.z, v);
                v = fmaf(ph[3], wv.w, v);
                xp[g][r] = v;
            }
        }
    }
    __syncthreads();   // phi consumed

    const int w    = tid >> 6;        // wave 0..7
    const int l    = tid & 63;
    const int col  = l & 15;          // C col / A row
    const int kp   = l >> 4;          // 0..3
    const int arow = col;
    const int asw  = (arow & 7) << 3; // short-unit XOR swizzle

    // transfer xp -> C-fragment layout via sbuf cols [0,256), one gate at a time
    f32x4 xpf[4][2];
    #pragma unroll 1
    for (int g = 0; g < 4; ++g) {
        #pragma unroll
        for (int r = 0; r < 8; ++r)
            sbuf[(rbase + r) * SSTR + j] = xp[g][r];
        __syncthreads();
        #pragma unroll
        for (int u = 0; u < 2; ++u)
            #pragma unroll
            for (int q = 0; q < 4; ++q)
                xpf[g][u][q] = sbuf[(kp * 4 + q) * SSTR + w * 32 + u * 16 + col];
        __syncthreads();
    }

    for (int i = tid; i < 16 * 256; i += 512) { hhi[0][i] = 0; hlo[0][i] = 0; }
    __syncthreads();

    const unsigned short* Bh = Wph + (size_t)l * 8;

    float c[2][4];
    #pragma unroll
    for (int u = 0; u < 2; ++u)
        #pragma unroll
        for (int q = 0; q < 4; ++q) c[u][q] = 0.0f;

    for (int t = 0; t < TSTEPS; ++t) {
        const short* Ahi = hhi[t & 1];
        const short* Alo = hlo[t & 1];
        short* Nhi = hhi[(t + 1) & 1];
        short* Nlo = hlo[(t + 1) & 1];

        float su[2];
        #pragma unroll 1
        for (int u = 0; u < 2; ++u) {
            f32x4 acc[4];
            #pragma unroll
            for (int g = 0; g < 4; ++g) acc[g] = xpf[g][u];

            #pragma unroll 2
            for (int ks = 0; ks < 8; ++ks) {
                bf16x8 bh[4];
                #pragma unroll
                for (int g = 0; g < 4; ++g)
                    bh[g] = *(const bf16x8*)(Bh +
                        (size_t)(((16 * g + 2 * w + u) * 8 + ks) * 64) * 8);
                bf16x8 ah = *(const bf16x8*)&Ahi[arow * 256 +
                                ((ks * 32 + kp * 8) ^ asw)];
                bf16x8 al = *(const bf16x8*)&Alo[arow * 256 +
                                ((ks * 32 + kp * 8) ^ asw)];
                #pragma unroll
                for (int g = 0; g < 4; ++g) {
                    acc[g] = __builtin_amdgcn_mfma_f32_16x16x32_bf16(al, bh[g], acc[g], 0, 0, 0);
                    acc[g] = __builtin_amdgcn_mfma_f32_16x16x32_bf16(ah, bh[g], acc[g], 0, 0, 0);
                }
            }

            float s = 0.0f;
            #pragma unroll
            for (int q = 0; q < 4; ++q) {
                float iv = sigmoidf_(acc[0][q]);
                float fv = sigmoidf_(acc[1][q]);
                float gv = tanhf_   (acc[2][q]);
                float ov = sigmoidf_(acc[3][q]);
                c[u][q] = fv * c[u][q] + iv * gv;
                float hv = ov * tanhf_(c[u][q]);
                s += hv;
                unsigned short h16 = f2bf_rne(hv);
                float lof = hv - bf2f(h16);
                int row  = kp * 4 + q;
                int hcol = w * 32 + u * 16 + col;
                int sidx = row * 256 + (hcol ^ ((row & 7) << 3));
                Nhi[sidx] = (short)h16;
                Nlo[sidx] = (short)f2bf_rne(lof);
            }
            su[u] = s;
        }

        #pragma unroll
        for (int u = 0; u < 2; ++u) {
            float v = su[u];
            v += __shfl_xor(v, 16);
            v += __shfl_xor(v, 32);
            if (l < 16)
                atomicAdd(&esum[t * GH + w * 32 + u * 16 + l], v);
        }
        __syncthreads();
    }
}

// ---------------------------------------------------------------------------
// Kernel C: proj[t][c] = (esum[t]/4096) @ W1_h + att_b1[c]
// ---------------------------------------------------------------------------
__global__ void proj_kernel(const float* __restrict__ esum,
                            const float* __restrict__ attW1,
                            const float* __restrict__ attb1,
                            float* __restrict__ proj)
{
    __shared__ float part[4][AH];
    const int t   = blockIdx.x;
    const int cix = threadIdx.x & 63;
    const int g   = threadIdx.x >> 6;
    float a = 0.0f;
    #pragma unroll 4
    for (int k = g * 64; k < g * 64 + 64; ++k) {
        float e = esum[t * GH + k] * (1.0f / (float)N_TRAIN);
        a = fmaf(e, attW1[(size_t)(N_TRAIN + k) * AH + cix], a);
    }
    part[g][cix] = a;
    __syncthreads();
    if (threadIdx.x < AH)
        proj[t * AH + cix] = part[0][cix] + part[1][cix] + part[2][cix] +
                             part[3][cix] + attb1[cix];
}

// ---------------------------------------------------------------------------
// Kernel D: S_proj fused with per-step scores — barrier-free, no LDS staging.
// Grid: 1024 blocks x 256 threads. Block owns 32 antes.
// Thread: ai = tid&7 -> antes a0+ai*4 (float4 S loads); cg = tid>>3 ->
// cols [cg*2, cg*2+2). acc = 4 antes x 2 cols = 8 regs.
// w read directly from global per row (float2, wave-broadcast, L2-resident
// 1 MB) -> ZERO barriers in the 4096-row loop, S prefetch never drains.
// 4 blocks/CU (launch_bounds(256,4)) -> 4 waves/SIMD TLP.
// ---------------------------------------------------------------------------
__global__ __launch_bounds__(256, 4) void scores_kernel(
    const float* __restrict__ S,
    const float* __restrict__ attW1,
    const float* __restrict__ proj,
    const float* __restrict__ attw2,
    const float* __restrict__ attb2,
    float* __restrict__ out)
{
    __shared__ float projl[TSTEPS * AH]; // 8 KB
    __shared__ float w2l[AH];
    __shared__ float part[32][33];       // 4.2 KB reduce buffer

    const int tid = threadIdx.x;
    const int ai  = tid & 7;             // ante quad within block
    const int cg  = tid >> 3;            // 0..31, cols cg*2..+2
    const int a0  = blockIdx.x * 32;
    const int a   = a0 + ai * 4;

    float acc[4][2];
    #pragma unroll
    for (int x = 0; x < 4; ++x) {
        acc[x][0] = 0.0f; acc[x][1] = 0.0f;
    }

    const float* Sp = S + a;
    const float* Wp = attW1 + cg * 2;

#define LS(dst, base_) do {                                                  \
        _Pragma("unroll") for (int i = 0; i < 4; ++i)                        \
            dst[i] = *(const float4*)(Sp + (size_t)((base_) + i) * NANTES);  \
    } while (0)

#define LW(dst, base_) do {                                                  \
        _Pragma("unroll") for (int i = 0; i < 4; ++i)                        \
            dst[i] = *(const float2*)(Wp + (size_t)((base_) + i) * AH);      \
    } while (0)

#define CS(src, wsrc) do {                                                   \
        _Pragma("unroll") for (int i = 0; i < 4; ++i) {                      \
            float2 wv = wsrc[i];                                             \
            float4 s4 = src[i];                                              \
            acc[0][0] = fmaf(s4.x, wv.x, acc[0][0]);                         \
            acc[0][1] = fmaf(s4.x, wv.y, acc[0][1]);                         \
            acc[1][0] = fmaf(s4.y, wv.x, acc[1][0]);                         \
            acc[1][1] = fmaf(s4.y, wv.y, acc[1][1]);                         \
            acc[2][0] = fmaf(s4.z, wv.x, acc[2][0]);                         \
            acc[2][1] = fmaf(s4.z, wv.y, acc[2][1]);                         \
            acc[3][0] = fmaf(s4.w, wv.x, acc[3][0]);                         \
            acc[3][1] = fmaf(s4.w, wv.y, acc[3][1]);                         \
        }                                                                    \
    } while (0)

    {
        float4 sA[4], sB[4];
        float2 wA[4], wB[4];
        LS(sA, 0); LW(wA, 0);
        #pragma unroll 2
        for (int g = 0; g < N_TRAIN / 8; ++g) {
            LS(sB, g * 8 + 4); LW(wB, g * 8 + 4);
            CS(sA, wA);
            if (g < N_TRAIN / 8 - 1) { LS(sA, g * 8 + 8); LW(wA, g * 8 + 8); }
            CS(sB, wB);
        }
    }
#undef LS
#undef LW
#undef CS

    for (int i = tid; i < TSTEPS * AH; i += 256) projl[i] = proj[i];
    if (tid < AH) w2l[tid] = attw2[tid];
    __syncthreads();

    const float b2v = attb2[0];
    const float w20 = w2l[cg * 2], w21 = w2l[cg * 2 + 1];
    #pragma unroll 1
    for (int t = 0; t < TSTEPS; ++t) {
        const float p0 = projl[t * AH + cg * 2];
        const float p1 = projl[t * AH + cg * 2 + 1];
        #pragma unroll
        for (int x = 0; x < 4; ++x)
            part[cg][ai * 4 + x] = fmaxf(acc[x][0] + p0, 0.0f) * w20 +
                                   fmaxf(acc[x][1] + p1, 0.0f) * w21;
        __syncthreads();
        if (tid < 32) {
            float v = b2v;
            #pragma unroll
            for (int g = 0; g < 32; ++g) v += part[g][tid];
            out[(size_t)t * NANTES + a0 + tid] = v;
        }
        __syncthreads();
    }
}

// ---------------------------------------------------------------------------
// Kernel E: per-step argmax (first-max semantics).
// ---------------------------------------------------------------------------
__global__ void argmax_kernel(const float* __restrict__ scores,
                              float* __restrict__ out)
{
    __shared__ float bv[256];
    __shared__ int   bidx[256];
    const int t = blockIdx.x, tid = threadIdx.x;
    float best = -INFINITY;
    int   bi   = 0x7fffffff;
    for (int a = tid; a < NANTES; a += 256) {
        float v = scores[(size_t)t * NANTES + a];
        if (v > best) { best = v; bi = a; }
    }
    bv[tid] = best; bidx[tid] = bi;
    __syncthreads();
    for (int s = 128; s > 0; s >>= 1) {
        if (tid < s) {
            if (bv[tid + s] > bv[tid] ||
                (bv[tid + s] == bv[tid] && bidx[tid + s] < bidx[tid])) {
                bv[tid] = bv[tid + s];
                bidx[tid] = bidx[tid + s];
            }
        }
        __syncthreads();
    }
    if (tid == 0)
        out[(size_t)TSTEPS * NANTES + t] = (float)bidx[0];
}

// ---------------------------------------------------------------------------
extern "C" void kernel_launch(void* const* d_in, const int* in_sizes, int n_in,
                              void* d_out, int out_size, void* d_ws, size_t ws_size,
                              hipStream_t stream)
{
    const float* ctx   = (const float*)d_in[0];
    const float* S     = (const float*)d_in[1];
    const float* encW1 = (const float*)d_in[2];
    const float* encb1 = (const float*)d_in[3];
    const float* encW2 = (const float*)d_in[4];
    const float* encb2 = (const float*)d_in[5];
    const float* Wih   = (const float*)d_in[6];
    const float* Whh   = (const float*)d_in[7];
    const float* bih   = (const float*)d_in[8];
    const float* bhh   = (const float*)d_in[9];
    const float* attW1 = (const float*)d_in[10];
    const float* attb1 = (const float*)d_in[11];
    const float* attw2 = (const float*)d_in[12];
    const float* attb2 = (const float*)d_in[13];

    char* ws = (char*)d_ws;
    float* esum = (float*)ws;                                // 32 KB
    float* proj = (float*)(ws + 32768);                      // 8 KB
    unsigned short* Wph = (unsigned short*)(ws + 40960);     // 512 KB
    float* out  = (float*)d_out;

    zero_kernel<<<dim3(8), dim3(256), 0, stream>>>(esum);
    pack_whh<<<dim3(128), dim3(256), 0, stream>>>(Whh, Wph);
    lstm_kernel<<<dim3(N_TRAIN / 16), dim3(512), 0, stream>>>(
        ctx, encW1, encb1, encW2, encb2, Wih, bih, bhh, Wph, esum);
    proj_kernel<<<dim3(TSTEPS), dim3(256), 0, stream>>>(esum, attW1, attb1, proj);
    scores_kernel<<<dim3(NANTES / 32), dim3(256), 0, stream>>>(
        S, attW1, proj, attw2, attb2, out);
    argmax_kernel<<<dim3(TSTEPS), dim3(256), 0, stream>>>(out, out);
}

// Round 10
// 642.785 us; speedup vs baseline: 2.8069x; 2.8069x over previous
//
#include <hip/hip_runtime.h>
#include <hip/hip_bf16.h>
#include <math.h>

// Problem constants
#define N_TRAIN 4096
#define N_FEAT  64
#define NHID    256
#define ENC     256
#define GH      256
#define AH      64
#define NANTES  32768
#define TSTEPS  32

#define SSTR 528   // lstm setup LDS row stride (f32)

typedef __attribute__((ext_vector_type(8))) short bf16x8;
typedef __attribute__((ext_vector_type(4))) float f32x4;

__device__ __forceinline__ float sigmoidf_(float x) {
    return 1.0f / (1.0f + __expf(-x));
}
__device__ __forceinline__ float tanhf_(float x) {
    return 1.0f - 2.0f / (__expf(2.0f * x) + 1.0f);
}
__device__ __forceinline__ unsigned short f2bf_rne(float x) {
    unsigned int u = __float_as_uint(x);
    unsigned int r = u + 0x7FFFu + ((u >> 16) & 1u);
    return (unsigned short)(r >> 16);
}
__device__ __forceinline__ float bf2f(unsigned short b) {
    return __uint_as_float(((unsigned int)b) << 16);
}

// ---------------------------------------------------------------------------
// Kernel 0: zero the e-sum accumulator
// ---------------------------------------------------------------------------
__global__ void zero_kernel(float* __restrict__ esum) {
    int tid = blockIdx.x * blockDim.x + threadIdx.x;
    for (int i = tid; i < TSTEPS * GH; i += gridDim.x * blockDim.x)
        esum[i] = 0.0f;
}

// ---------------------------------------------------------------------------
// Kernel P: pack Whh (1024x256 f32) into MFMA-fragment-ordered bf16 (hi only).
// ---------------------------------------------------------------------------
__global__ void pack_whh(const float* __restrict__ Whh,
                         unsigned short* __restrict__ hi)
{
    int g = blockIdx.x * 256 + threadIdx.x;      // 0 .. 32767
    if (g >= 64 * 8 * 64) return;
    int lane  = g & 63;
    int ks    = (g >> 6) & 7;
    int ntile = g >> 9;
    int n  = ntile * 16 + (lane & 15);
    int k0 = ks * 32 + (lane >> 4) * 8;
    const float* src = Whh + n * 256 + k0;
    #pragma unroll
    for (int j = 0; j < 8; ++j)
        hi[g * 8 + j] = f2bf_rne(src[j]);
}

// ---------------------------------------------------------------------------
// Kernel P2: pack attW1[:4096] (4096x64 f32, k-major) into MFMA B-fragment
// order, bf16 hi/lo. Group g = ((ct*128 + ks)*64 + lane):
//   value W[k][n] with n = ct*16 + (lane&15), k = ks*32 + (lane>>4)*8 + j.
// ---------------------------------------------------------------------------
__global__ void pack_wa(const float* __restrict__ attW1,
                        unsigned short* __restrict__ hi,
                        unsigned short* __restrict__ lo)
{
    int g = blockIdx.x * 256 + threadIdx.x;      // 0 .. 32767
    if (g >= 4 * 128 * 64) return;
    int lane = g & 63;
    int ks   = (g >> 6) & 127;
    int ct   = g >> 13;
    int n  = ct * 16 + (lane & 15);
    int k0 = ks * 32 + (lane >> 4) * 8;
    const float* src = attW1 + (size_t)k0 * AH + n;
    #pragma unroll
    for (int j = 0; j < 8; ++j) {
        float x = src[(size_t)j * AH];
        unsigned short h16 = f2bf_rne(x);
        hi[g * 8 + j] = h16;
        lo[g * 8 + j] = f2bf_rne(x - bf2f(h16));
    }
}

// ---------------------------------------------------------------------------
// Kernel A: fused encoder -> x_proj -> 32-step MFMA LSTM -> per-step h sums
// (unchanged from round 6)
// ---------------------------------------------------------------------------
__global__ __launch_bounds__(512, 4) void lstm_kernel(
    const float* __restrict__ ctx,
    const float* __restrict__ encW1, const float* __restrict__ encb1,
    const float* __restrict__ encW2, const float* __restrict__ encb2,
    const float* __restrict__ Wih,
    const float* __restrict__ bih,  const float* __restrict__ bhh,
    const unsigned short* __restrict__ Wph,
    float* __restrict__ esum)
{
    __shared__ float sbuf[16 * SSTR];      // 33792 B setup scratch
    __shared__ short hhi[2][16 * 256];     // 16 KB, XOR-swizzled cols
    __shared__ short hlo[2][16 * 256];     // 16 KB

    const int tid   = threadIdx.x;
    const int j     = tid & 255;
    const int rh    = tid >> 8;
    const int rbase = rh * 8;
    const int r0    = blockIdx.x * 16;

    // hid = relu(ctx @ encW1 + b1) -> sbuf cols [0,256)
    {
        float acc[8];
        float b = encb1[j];
        #pragma unroll
        for (int r = 0; r < 8; ++r) acc[r] = b;
        for (int k = 0; k < N_FEAT; ++k) {
            float w = encW1[k * NHID + j];
            #pragma unroll
            for (int r = 0; r < 8; ++r)
                acc[r] = fmaf(ctx[(r0 + rbase + r) * N_FEAT + k], w, acc[r]);
        }
        #pragma unroll
        for (int r = 0; r < 8; ++r)
            sbuf[(rbase + r) * SSTR + j] = fmaxf(acc[r], 0.0f);
    }
    __syncthreads();

    // phi = hid @ encW2 + b2 -> sbuf cols [264,520)
    {
        float p[8];
        float b = encb2[j];
        #pragma unroll
        for (int r = 0; r < 8; ++r) p[r] = b;
        for (int k = 0; k < NHID; ++k) {
            float w = encW2[k * ENC + j];
            #pragma unroll
            for (int r = 0; r < 8; ++r)
                p[r] = fmaf(sbuf[(rbase + r) * SSTR + k], w, p[r]);
        }
        __syncthreads();
        #pragma unroll
        for (int r = 0; r < 8; ++r)
            sbuf[(rbase + r) * SSTR + 264 + j] = p[r];
    }
    __syncthreads();

    // xp[g][r] in registers (reads phi)
    float xp[4][8];
    #pragma unroll
    for (int g = 0; g < 4; ++g) {
        int m = g * 256 + j;
        float b = bih[m] + bhh[m];
        #pragma unroll
        for (int r = 0; r < 8; ++r) xp[g][r] = b;
        const float4* wrow = (const float4*)(Wih + m * ENC);
        for (int k4 = 0; k4 < ENC / 4; ++k4) {
            float4 wv = wrow[k4];
            #pragma unroll
            for (int r = 0; r < 8; ++r) {
                const float* ph = &sbuf[(rbase + r) * SSTR + 264 + k4 * 4];
                float v = xp[g][r];
                v = fmaf(ph[0], wv.x, v);
                v = fmaf(ph[1], wv.y, v);
                v = fmaf(ph[2], wv.z, v);
                v = fmaf(ph[3], wv.w, v);
                xp[g][r] = v;
            }
        }
    }
    __syncthreads();   // phi consumed

    const int w    = tid >> 6;        // wave 0..7
    const int l    = tid & 63;
    const int col  = l & 15;          // C col / A row
    const int kp   = l >> 4;          // 0..3
    const int arow = col;
    const int asw  = (arow & 7) << 3; // short-unit XOR swizzle

    // transfer xp -> C-fragment layout via sbuf cols [0,256), one gate at a time
    f32x4 xpf[4][2];
    #pragma unroll 1
    for (int g = 0; g < 4; ++g) {
        #pragma unroll
        for (int r = 0; r < 8; ++r)
            sbuf[(rbase + r) * SSTR + j] = xp[g][r];
        __syncthreads();
        #pragma unroll
        for (int u = 0; u < 2; ++u)
            #pragma unroll
            for (int q = 0; q < 4; ++q)
                xpf[g][u][q] = sbuf[(kp * 4 + q) * SSTR + w * 32 + u * 16 + col];
        __syncthreads();
    }

    for (int i = tid; i < 16 * 256; i += 512) { hhi[0][i] = 0; hlo[0][i] = 0; }
    __syncthreads();

    const unsigned short* Bh = Wph + (size_t)l * 8;

    float c[2][4];
    #pragma unroll
    for (int u = 0; u < 2; ++u)
        #pragma unroll
        for (int q = 0; q < 4; ++q) c[u][q] = 0.0f;

    for (int t = 0; t < TSTEPS; ++t) {
        const short* Ahi = hhi[t & 1];
        const short* Alo = hlo[t & 1];
        short* Nhi = hhi[(t + 1) & 1];
        short* Nlo = hlo[(t + 1) & 1];

        float su[2];
        #pragma unroll 1
        for (int u = 0; u < 2; ++u) {
            f32x4 acc[4];
            #pragma unroll
            for (int g = 0; g < 4; ++g) acc[g] = xpf[g][u];

            #pragma unroll 2
            for (int ks = 0; ks < 8; ++ks) {
                bf16x8 bh[4];
                #pragma unroll
                for (int g = 0; g < 4; ++g)
                    bh[g] = *(const bf16x8*)(Bh +
                        (size_t)(((16 * g + 2 * w + u) * 8 + ks) * 64) * 8);
                bf16x8 ah = *(const bf16x8*)&Ahi[arow * 256 +
                                ((ks * 32 + kp * 8) ^ asw)];
                bf16x8 al = *(const bf16x8*)&Alo[arow * 256 +
                                ((ks * 32 + kp * 8) ^ asw)];
                #pragma unroll
                for (int g = 0; g < 4; ++g) {
                    acc[g] = __builtin_amdgcn_mfma_f32_16x16x32_bf16(al, bh[g], acc[g], 0, 0, 0);
                    acc[g] = __builtin_amdgcn_mfma_f32_16x16x32_bf16(ah, bh[g], acc[g], 0, 0, 0);
                }
            }

            float s = 0.0f;
            #pragma unroll
            for (int q = 0; q < 4; ++q) {
                float iv = sigmoidf_(acc[0][q]);
                float fv = sigmoidf_(acc[1][q]);
                float gv = tanhf_   (acc[2][q]);
                float ov = sigmoidf_(acc[3][q]);
                c[u][q] = fv * c[u][q] + iv * gv;
                float hv = ov * tanhf_(c[u][q]);
                s += hv;
                unsigned short h16 = f2bf_rne(hv);
                float lof = hv - bf2f(h16);
                int row  = kp * 4 + q;
                int hcol = w * 32 + u * 16 + col;
                int sidx = row * 256 + (hcol ^ ((row & 7) << 3));
                Nhi[sidx] = (short)h16;
                Nlo[sidx] = (short)f2bf_rne(lof);
            }
            su[u] = s;
        }

        #pragma unroll
        for (int u = 0; u < 2; ++u) {
            float v = su[u];
            v += __shfl_xor(v, 16);
            v += __shfl_xor(v, 32);
            if (l < 16)
                atomicAdd(&esum[t * GH + w * 32 + u * 16 + l], v);
        }
        __syncthreads();
    }
}

// ---------------------------------------------------------------------------
// Kernel C: proj[t][c] = (esum[t]/4096) @ W1_h + att_b1[c]
// ---------------------------------------------------------------------------
__global__ void proj_kernel(const float* __restrict__ esum,
                            const float* __restrict__ attW1,
                            const float* __restrict__ attb1,
                            float* __restrict__ proj)
{
    __shared__ float part[4][AH];
    const int t   = blockIdx.x;
    const int cix = threadIdx.x & 63;
    const int g   = threadIdx.x >> 6;
    float a = 0.0f;
    #pragma unroll 4
    for (int k = g * 64; k < g * 64 + 64; ++k) {
        float e = esum[t * GH + k] * (1.0f / (float)N_TRAIN);
        a = fmaf(e, attW1[(size_t)(N_TRAIN + k) * AH + cix], a);
    }
    part[g][cix] = a;
    __syncthreads();
    if (threadIdx.x < AH)
        proj[t * AH + cix] = part[0][cix] + part[1][cix] + part[2][cix] +
                             part[3][cix] + attb1[cix];
}

// ---------------------------------------------------------------------------
// Kernel D: S_proj via MFMA (4-term bf16 hi/lo split -> ~f32 accuracy),
// fused per-step scores epilogue.
// Grid: 256 blocks x 512 threads (8 waves). Wave wv owns antes
// [blk*128 + wv*16, +16) x all 64 cols. A-frag (S^T) read DIRECTLY from
// global: lane l reads S[k][a0+(l&15)], k = ks*32 + (l>>4)*8 + j -> each
// load instr = 4 rows x 64 B contiguous. 2-chunk register ping-pong,
// ZERO barriers in the K-loop. B-frags from pre-packed bf16 hi/lo (L2-hot).
// ---------------------------------------------------------------------------
__global__ __launch_bounds__(512, 4) void scores_kernel(
    const float* __restrict__ S,
    const unsigned short* __restrict__ Wah,
    const unsigned short* __restrict__ Wal,
    const float* __restrict__ proj,
    const float* __restrict__ attw2,
    const float* __restrict__ attb2,
    float* __restrict__ out)
{
    __shared__ float projl[TSTEPS * AH]; // 8 KB
    __shared__ float w2l[AH];

    const int tid   = threadIdx.x;
    const int wv    = tid >> 6;          // 0..7: ante-tile
    const int l     = tid & 63;
    const int kp    = l >> 4;            // 0..3
    const int atile = blockIdx.x * 128 + wv * 16;
    const int an    = atile + (l & 15);  // this lane's A-row (ante)

    f32x4 acc[4];
    #pragma unroll
    for (int ct = 0; ct < 4; ++ct) acc[ct] = (f32x4){0.f, 0.f, 0.f, 0.f};

    const float* Sp = S + an;
    const unsigned short* Bh = Wah + (size_t)l * 8;
    const unsigned short* Bl = Wal + (size_t)l * 8;

#define LOADS(dst, ks_) do {                                                 \
        _Pragma("unroll") for (int jj = 0; jj < 8; ++jj)                     \
            dst[jj] = Sp[(size_t)(32 * (ks_) + kp * 8 + jj) * NANTES];       \
    } while (0)

    float sA[8], sB[8];
    LOADS(sA, 0);
    LOADS(sB, 1);

    #pragma unroll 2
    for (int ks = 0; ks < 128; ++ks) {
        // issue B loads first (L2), overlap with conversion VALU
        bf16x8 bh[4], bl[4];
        #pragma unroll
        for (int ct = 0; ct < 4; ++ct) {
            size_t off = (size_t)((ct * 128 + ks) * 64) * 8;
            bh[ct] = *(const bf16x8*)(Bh + off);
            bl[ct] = *(const bf16x8*)(Bl + off);
        }

        // convert current S chunk to bf16 hi/lo fragments
        float* cur = (ks & 1) ? sB : sA;
        bf16x8 ah, al;
        #pragma unroll
        for (int jj = 0; jj < 8; ++jj) {
            float x = cur[jj];
            unsigned short h16 = f2bf_rne(x);
            ah[jj] = (short)h16;
            al[jj] = (short)f2bf_rne(x - bf2f(h16));
        }

        // prefetch chunk ks+2 into the buffer just consumed
        if (ks < 126) LOADS(cur, ks + 2);

        #pragma unroll
        for (int ct = 0; ct < 4; ++ct) {
            acc[ct] = __builtin_amdgcn_mfma_f32_16x16x32_bf16(al, bl[ct], acc[ct], 0, 0, 0);
            acc[ct] = __builtin_amdgcn_mfma_f32_16x16x32_bf16(al, bh[ct], acc[ct], 0, 0, 0);
            acc[ct] = __builtin_amdgcn_mfma_f32_16x16x32_bf16(ah, bl[ct], acc[ct], 0, 0, 0);
            acc[ct] = __builtin_amdgcn_mfma_f32_16x16x32_bf16(ah, bh[ct], acc[ct], 0, 0, 0);
        }
    }
#undef LOADS

    // ---- epilogue ----
    for (int i = tid; i < TSTEPS * AH; i += 512) projl[i] = proj[i];
    if (tid < AH) w2l[tid] = attw2[tid];
    __syncthreads();

    const float b2v = attb2[0];
    const int cn = l & 15;               // C col within tile
    #pragma unroll 1
    for (int t = 0; t < TSTEPS; ++t) {
        #pragma unroll
        for (int q = 0; q < 4; ++q) {
            float sc = 0.0f;
            #pragma unroll
            for (int ct = 0; ct < 4; ++ct) {
                int colg = ct * 16 + cn;
                sc += fmaxf(acc[ct][q] + projl[t * AH + colg], 0.0f) * w2l[colg];
            }
            sc += __shfl_xor(sc, 1);
            sc += __shfl_xor(sc, 2);
            sc += __shfl_xor(sc, 4);
            sc += __shfl_xor(sc, 8);
            if (cn == 0)
                out[(size_t)t * NANTES + atile + kp * 4 + q] = sc + b2v;
        }
    }
}

// ---------------------------------------------------------------------------
// Kernel E: per-step argmax (first-max semantics).
// ---------------------------------------------------------------------------
__global__ void argmax_kernel(const float* __restrict__ scores,
                              float* __restrict__ out)
{
    __shared__ float bv[256];
    __shared__ int   bidx[256];
    const int t = blockIdx.x, tid = threadIdx.x;
    float best = -INFINITY;
    int   bi   = 0x7fffffff;
    for (int a = tid; a < NANTES; a += 256) {
        float v = scores[(size_t)t * NANTES + a];
        if (v > best) { best = v; bi = a; }
    }
    bv[tid] = best; bidx[tid] = bi;
    __syncthreads();
    for (int s = 128; s > 0; s >>= 1) {
        if (tid < s) {
            if (bv[tid + s] > bv[tid] ||
                (bv[tid + s] == bv[tid] && bidx[tid + s] < bidx[tid])) {
                bv[tid] = bv[tid + s];
                bidx[tid] = bidx[tid + s];
            }
        }
        __syncthreads();
    }
    if (tid == 0)
        out[(size_t)TSTEPS * NANTES + t] = (float)bidx[0];
}

// ---------------------------------------------------------------------------
extern "C" void kernel_launch(void* const* d_in, const int* in_sizes, int n_in,
                              void* d_out, int out_size, void* d_ws, size_t ws_size,
                              hipStream_t stream)
{
    const float* ctx   = (const float*)d_in[0];
    const float* S     = (const float*)d_in[1];
    const float* encW1 = (const float*)d_in[2];
    const float* encb1 = (const float*)d_in[3];
    const float* encW2 = (const float*)d_in[4];
    const float* encb2 = (const float*)d_in[5];
    const float* Wih   = (const float*)d_in[6];
    const float* Whh   = (const float*)d_in[7];
    const float* bih   = (const float*)d_in[8];
    const float* bhh   = (const float*)d_in[9];
    const float* attW1 = (const float*)d_in[10];
    const float* attb1 = (const float*)d_in[11];
    const float* attw2 = (const float*)d_in[12];
    const float* attb2 = (const float*)d_in[13];

    char* ws = (char*)d_ws;
    float* esum = (float*)ws;                                     // 32 KB
    float* proj = (float*)(ws + 32768);                           // 8 KB
    unsigned short* Wph = (unsigned short*)(ws + 40960);          // 512 KB
    unsigned short* Wah = (unsigned short*)(ws + 40960 + 524288); // 512 KB
    unsigned short* Wal = (unsigned short*)(ws + 40960 + 1048576);// 512 KB
    float* out  = (float*)d_out;

    zero_kernel<<<dim3(8), dim3(256), 0, stream>>>(esum);
    pack_whh<<<dim3(128), dim3(256), 0, stream>>>(Whh, Wph);
    pack_wa<<<dim3(128), dim3(256), 0, stream>>>(attW1, Wah, Wal);
    lstm_kernel<<<dim3(N_TRAIN / 16), dim3(512), 0, stream>>>(
        ctx, encW1, encb1, encW2, encb2, Wih, bih, bhh, Wph, esum);
    proj_kernel<<<dim3(TSTEPS), dim3(256), 0, stream>>>(esum, attW1, attb1, proj);
    scores_kernel<<<dim3(NANTES / 128), dim3(512), 0, stream>>>(
        S, Wah, Wal, proj, attw2, attb2, out);
    argmax_kernel<<<dim3(TSTEPS), dim3(256), 0, stream>>>(out, out);
}